// Round 1
// baseline (625.634 us; speedup 1.0000x reference)
//
#include <hip/hip_runtime.h>
#include <hip/hip_bf16.h>
#include <stdint.h>

// R1: GPTQ int4 dequant + GEMM, M=8192 K=4096 N=4096, fp32 in/out.
// Structure: two memory-bound pre-passes (x->bf16, unpack W -> W^T bf16),
// then m97-style 128x128 bf16 MFMA GEMM (2-barrier K-loop, global_load_lds w16).
// ws layout: [0, 64MB) x_bf16 [M][K]; [64MB, 96MB) Wt bf16 [N][K]. Needs 96 MiB ws.

#define M_DIM 8192
#define K_DIM 4096
#define N_DIM 4096

#define BM 128
#define BN 128
#define BK 64

typedef __attribute__((ext_vector_type(8))) short s16x8;
typedef __attribute__((ext_vector_type(8))) unsigned short u16x8;
typedef __attribute__((ext_vector_type(4))) float f32x4;
typedef unsigned int u32;

#define AS1 __attribute__((address_space(1)))
#define AS3 __attribute__((address_space(3)))

__device__ __forceinline__ void gload_lds16(const void* g, void* l) {
    __builtin_amdgcn_global_load_lds((const AS1 u32*)g, (AS3 u32*)l, 16, 0, 0);
}

__device__ __forceinline__ unsigned short f32_to_bf16_rne(float f) {
    union { float f; u32 u; } v; v.f = f;
    u32 u = v.u;
    u32 r = (u + 0x7FFFu + ((u >> 16) & 1u)) >> 16;
    return (unsigned short)r;
}

// ---- pre-pass 1: x fp32 -> bf16, [M][K] row-major. 8 elems/thread. ----
__global__ __launch_bounds__(256) void cvt_x_bf16(const float* __restrict__ in,
                                                  unsigned short* __restrict__ out) {
    const int i = blockIdx.x * 256 + threadIdx.x;       // 0 .. M*K/8-1 (exact grid)
    const f32x4* p = (const f32x4*)in + (size_t)i * 2;
    f32x4 a = p[0], b = p[1];
    u16x8 r;
    r[0] = f32_to_bf16_rne(a[0]); r[1] = f32_to_bf16_rne(a[1]);
    r[2] = f32_to_bf16_rne(a[2]); r[3] = f32_to_bf16_rne(a[3]);
    r[4] = f32_to_bf16_rne(b[0]); r[5] = f32_to_bf16_rne(b[1]);
    r[6] = f32_to_bf16_rne(b[2]); r[7] = f32_to_bf16_rne(b[3]);
    ((u16x8*)out)[i] = r;
}

// ---- pre-pass 2: unpack GPTQ nibbles, dequant, store W^T bf16 [N][K]. ----
// thread = one packed word (kp, n): 8 consecutive k for one n -> one 16B store.
__global__ __launch_bounds__(256) void dequant_wt(const int* __restrict__ qw,
                                                  const float* __restrict__ scales,
                                                  unsigned short* __restrict__ wt) {
    const int idx = blockIdx.x * 256 + threadIdx.x;     // kp*N + n, n fastest (coalesced reads)
    const int n  = idx & (N_DIM - 1);
    const int kp = idx >> 12;                           // log2(N_DIM)=12
    const u32 q = ((const u32*)qw)[idx];
    const float s = scales[(size_t)(kp >> 4) * N_DIM + n];   // group = kp*8/128 = kp/16
    u16x8 r;
#pragma unroll
    for (int j = 0; j < 8; j++) {
        const int w = (int)((q >> (4 * j)) & 0xFu) - 8;      // uint4b8: zp = 8
        r[j] = f32_to_bf16_rne((float)w * s);
    }
    *(u16x8*)(&wt[(size_t)n * K_DIM + (size_t)kp * 8]) = r;
}

// ---- GEMM: C[M][N] fp32 = A[M][K]bf16 * Bt[N][K]bf16^T ----
// 256 thr = 4 waves (2x2), wave owns 64x64 = 4x4 frags of 16x16x32 MFMA.
// LDS: As[128][64], Bs[128][64] linear row-major, staged via global_load_lds w16.
__global__ __launch_bounds__(256) void gemm_bf16_bt(const unsigned short* __restrict__ A,
                                                    const unsigned short* __restrict__ Bt,
                                                    float* __restrict__ C) {
    __shared__ unsigned short As[BM * BK];
    __shared__ unsigned short Bs[BN * BK];

    const int tid  = threadIdx.x;
    const int wave = tid >> 6;
    const int lane = tid & 63;

    // XCD-aware swizzle: grid = 2048, divisible by 8 -> simple form is bijective.
    const int nwg = gridDim.x;
    const int cpx = nwg >> 3;
    const int bid = blockIdx.x;
    const int wg  = (bid & 7) * cpx + (bid >> 3);

    const int nbn = N_DIM / BN;                 // 32
    const int m0 = (wg / nbn) * BM;
    const int n0 = (wg % nbn) * BN;

    const int wm = wave >> 1;                   // 0..1
    const int wn = wave & 1;                    // 0..1

    // staging: chunk c = wave*4+i covers rows c*8..c*8+7 of the tile (1KB/chunk).
    const int srow = lane >> 3;                 // 0..7
    const int scol = (lane & 7) * 8;            // element col within BK
    const unsigned short* gA = A  + (size_t)(m0 + wave * 32 + srow) * K_DIM + scol;
    const unsigned short* gB = Bt + (size_t)(n0 + wave * 32 + srow) * K_DIM + scol;

    // fragment read base: lane&15 = row within frag, lane>>4 = K-octet.
    const int fr = lane & 15;
    const int fq = lane >> 4;                   // 0..3
    const unsigned short* lA = &As[(size_t)(wm * 64 + fr) * BK + fq * 8];
    const unsigned short* lB = &Bs[(size_t)(wn * 64 + fr) * BK + fq * 8];

    f32x4 acc[4][4] = {};

    for (int k0 = 0; k0 < K_DIM; k0 += BK) {
#pragma unroll
        for (int i = 0; i < 4; i++) {
            gload_lds16(gA + (size_t)i * 8 * K_DIM + k0, &As[(wave * 4 + i) * 512]);
            gload_lds16(gB + (size_t)i * 8 * K_DIM + k0, &Bs[(wave * 4 + i) * 512]);
        }
        __syncthreads();                        // compiler drains vmcnt before barrier
#pragma unroll
        for (int kk = 0; kk < BK; kk += 32) {
            s16x8 af[4], bfr[4];
#pragma unroll
            for (int m = 0; m < 4; m++) af[m]  = *(const s16x8*)(lA + m * 16 * BK + kk);
#pragma unroll
            for (int n = 0; n < 4; n++) bfr[n] = *(const s16x8*)(lB + n * 16 * BK + kk);
#pragma unroll
            for (int m = 0; m < 4; m++)
#pragma unroll
                for (int n = 0; n < 4; n++)
                    acc[m][n] = __builtin_amdgcn_mfma_f32_16x16x32_bf16(
                        af[m], bfr[n], acc[m][n], 0, 0, 0);
        }
        __syncthreads();
    }

    // epilogue: C/D layout col=lane&15, row=(lane>>4)*4+reg (m89-verified).
#pragma unroll
    for (int m = 0; m < 4; m++) {
        const int row = m0 + wm * 64 + m * 16 + fq * 4;
#pragma unroll
        for (int n = 0; n < 4; n++) {
            const int col = n0 + wn * 64 + n * 16 + fr;
            float* cp = C + (size_t)row * N_DIM + col;
#pragma unroll
            for (int r = 0; r < 4; r++) cp[(size_t)r * N_DIM] = acc[m][n][r];
        }
    }
}

extern "C" void kernel_launch(void* const* d_in, const int* in_sizes, int n_in,
                              void* d_out, int out_size, void* d_ws, size_t ws_size,
                              hipStream_t stream) {
    const float* x  = (const float*)d_in[0];
    const int*   qw = (const int*)d_in[1];
    const float* sc = (const float*)d_in[2];
    float* out = (float*)d_out;

    unsigned short* xbf = (unsigned short*)d_ws;                               // 64 MiB
    unsigned short* wt  = (unsigned short*)((char*)d_ws + (size_t)M_DIM * K_DIM * 2); // 32 MiB

    cvt_x_bf16<<<(M_DIM * (size_t)K_DIM) / 8 / 256, 256, 0, stream>>>(x, xbf);
    dequant_wt<<<((K_DIM / 8) * (size_t)N_DIM) / 256, 256, 0, stream>>>(qw, sc, wt);
    gemm_bf16_bt<<<(M_DIM / BM) * (N_DIM / BN), 256, 0, stream>>>(xbf, wt, out);
}

// Round 2
// 524.759 us; speedup vs baseline: 1.1922x; 1.1922x over previous
//
#include <hip/hip_runtime.h>
#include <hip/hip_bf16.h>
#include <stdint.h>

// R2: GPTQ int4 dequant + GEMM, M=8192 K=4096 N=4096, fp32 in/out.
// Changes vs R1:
//  - GEMM: both-sides XOR swizzle (pre-swizzled global source octet for
//    global_load_lds + XOR'd fragment-read octet) to kill the 16-way LDS
//    bank conflict (1.0e8 conflict cycles in R1).
//  - dequant_wt: wave covers 16 kp x 4 n so W^T writes are 256B-contiguous
//    per row (R1 wrote scattered 16B at 8KB stride -> write amplification).
// ws layout: [0, 64MB) x_bf16 [M][K]; [64MB, 96MB) Wt bf16 [N][K].

#define M_DIM 8192
#define K_DIM 4096
#define N_DIM 4096

#define BM 128
#define BN 128
#define BK 64

typedef __attribute__((ext_vector_type(8))) short s16x8;
typedef __attribute__((ext_vector_type(8))) unsigned short u16x8;
typedef __attribute__((ext_vector_type(4))) float f32x4;
typedef unsigned int u32;

#define AS1 __attribute__((address_space(1)))
#define AS3 __attribute__((address_space(3)))

__device__ __forceinline__ void gload_lds16(const void* g, void* l) {
    __builtin_amdgcn_global_load_lds((const AS1 u32*)g, (AS3 u32*)l, 16, 0, 0);
}

__device__ __forceinline__ unsigned short f32_to_bf16_rne(float f) {
    union { float f; u32 u; } v; v.f = f;
    u32 u = v.u;
    u32 r = (u + 0x7FFFu + ((u >> 16) & 1u)) >> 16;
    return (unsigned short)r;
}

// ---- pre-pass 1: x fp32 -> bf16, [M][K] row-major. 8 elems/thread. ----
__global__ __launch_bounds__(256) void cvt_x_bf16(const float* __restrict__ in,
                                                  unsigned short* __restrict__ out) {
    const int i = blockIdx.x * 256 + threadIdx.x;       // 0 .. M*K/8-1 (exact grid)
    const f32x4* p = (const f32x4*)in + (size_t)i * 2;
    f32x4 a = p[0], b = p[1];
    u16x8 r;
    r[0] = f32_to_bf16_rne(a[0]); r[1] = f32_to_bf16_rne(a[1]);
    r[2] = f32_to_bf16_rne(a[2]); r[3] = f32_to_bf16_rne(a[3]);
    r[4] = f32_to_bf16_rne(b[0]); r[5] = f32_to_bf16_rne(b[1]);
    r[6] = f32_to_bf16_rne(b[2]); r[7] = f32_to_bf16_rne(b[3]);
    ((u16x8*)out)[i] = r;
}

// ---- pre-pass 2: unpack GPTQ nibbles, dequant, store W^T bf16 [N][K]. ----
// Block tile: 16 kp (=128 k) x 16 n. Wave covers 16 kp x 4 n so the 16B
// stores of 16 consecutive kp for one n merge into 256B contiguous runs.
__global__ __launch_bounds__(256) void dequant_wt(const int* __restrict__ qw,
                                                  const float* __restrict__ scales,
                                                  unsigned short* __restrict__ wt) {
    const int bid = blockIdx.x;
    const int nb  = (bid & (N_DIM / 16 - 1)) * 16;      // 256 n-tiles
    const int kpb = (bid >> 8) * 16;                    // 32 kp-tiles
    const int tid = threadIdx.x;
    const int n   = nb + ((tid >> 6) << 2) + (tid & 3);     // 16 distinct n
    const int kp  = kpb + ((tid >> 2) & 15);                // 16 distinct kp
    const u32 q = ((const u32*)qw)[(size_t)kp * N_DIM + n];
    const float s = scales[(size_t)(kp >> 4) * N_DIM + n];  // group = kp/16
    u16x8 r;
#pragma unroll
    for (int j = 0; j < 8; j++) {
        const int w = (int)((q >> (4 * j)) & 0xFu) - 8;     // uint4b8: zp = 8
        r[j] = f32_to_bf16_rne((float)w * s);
    }
    *(u16x8*)(&wt[(size_t)n * K_DIM + (size_t)kp * 8]) = r;
}

// ---- GEMM: C[M][N] fp32 = A[M][K]bf16 * Bt[N][K]bf16^T ----
// 256 thr = 4 waves (2x2), wave owns 64x64 = 4x4 frags of 16x16x32 MFMA.
// LDS: As[128][64], Bs[128][64], linear dest for global_load_lds w16; the
// CONTENT is octet-swizzled: LDS slot (row, c') holds global k-octet
// c' ^ (row&7). Fragment reads XOR the same way -> conflict-free (2-way max).
__global__ __launch_bounds__(256) void gemm_bf16_bt(const unsigned short* __restrict__ A,
                                                    const unsigned short* __restrict__ Bt,
                                                    float* __restrict__ C) {
    __shared__ unsigned short As[BM * BK];
    __shared__ unsigned short Bs[BN * BK];

    const int tid  = threadIdx.x;
    const int wave = tid >> 6;
    const int lane = tid & 63;

    // XCD-aware swizzle: grid = 2048, divisible by 8 -> simple form bijective.
    const int nwg = gridDim.x;
    const int cpx = nwg >> 3;
    const int bid = blockIdx.x;
    const int wg  = (bid & 7) * cpx + (bid >> 3);

    const int nbn = N_DIM / BN;                 // 32
    const int m0 = (wg / nbn) * BM;
    const int n0 = (wg % nbn) * BN;

    const int wm = wave >> 1;                   // 0..1
    const int wn = wave & 1;                    // 0..1

    // staging: chunk c = wave*4+i covers rows c*8..c*8+7 of the tile (1KB).
    // Pre-swizzled source octet: lane l supplies k-octet (l&7)^(l>>3) of its
    // row, so LDS slot (r, c') = global octet c'^r.  (rule #21: swizzle the
    // SOURCE + the READ, keep global_load_lds dest linear.)
    const int srow = lane >> 3;                               // 0..7
    const int scol = ((lane & 7) ^ (lane >> 3)) * 8;          // swizzled octet
    const unsigned short* gA = A  + (size_t)(m0 + wave * 32 + srow) * K_DIM + scol;
    const unsigned short* gB = Bt + (size_t)(n0 + wave * 32 + srow) * K_DIM + scol;

    // fragment read: row = (wm|wn)*64 + m*16 + fr; octet = (fq + kk/8) ^ (fr&7)
    const int fr = lane & 15;
    const int fq = lane >> 4;                   // 0..3
    const int r7 = fr & 7;
    const unsigned short* lA = &As[(size_t)(wm * 64 + fr) * BK];
    const unsigned short* lB = &Bs[(size_t)(wn * 64 + fr) * BK];

    f32x4 acc[4][4] = {};

    for (int k0 = 0; k0 < K_DIM; k0 += BK) {
#pragma unroll
        for (int i = 0; i < 4; i++) {
            gload_lds16(gA + (size_t)i * 8 * K_DIM + k0, &As[(wave * 4 + i) * 512]);
            gload_lds16(gB + (size_t)i * 8 * K_DIM + k0, &Bs[(wave * 4 + i) * 512]);
        }
        __syncthreads();                        // compiler drains vmcnt before barrier
#pragma unroll
        for (int kk = 0; kk < BK; kk += 32) {
            const int kko = kk >> 3;            // 0 or 4
            s16x8 af[4], bfr[4];
#pragma unroll
            for (int m = 0; m < 4; m++)
                af[m]  = *(const s16x8*)(lA + m * 16 * BK + (((fq + kko) ^ r7) << 3));
#pragma unroll
            for (int n = 0; n < 4; n++)
                bfr[n] = *(const s16x8*)(lB + n * 16 * BK + (((fq + kko) ^ r7) << 3));
#pragma unroll
            for (int m = 0; m < 4; m++)
#pragma unroll
                for (int n = 0; n < 4; n++)
                    acc[m][n] = __builtin_amdgcn_mfma_f32_16x16x32_bf16(
                        af[m], bfr[n], acc[m][n], 0, 0, 0);
        }
        __syncthreads();
    }

    // epilogue: C/D layout col=lane&15, row=(lane>>4)*4+reg (m89-verified).
#pragma unroll
    for (int m = 0; m < 4; m++) {
        const int row = m0 + wm * 64 + m * 16 + fq * 4;
#pragma unroll
        for (int n = 0; n < 4; n++) {
            const int col = n0 + wn * 64 + n * 16 + fr;
            float* cp = C + (size_t)row * N_DIM + col;
#pragma unroll
            for (int r = 0; r < 4; r++) cp[(size_t)r * N_DIM] = acc[m][n][r];
        }
    }
}

extern "C" void kernel_launch(void* const* d_in, const int* in_sizes, int n_in,
                              void* d_out, int out_size, void* d_ws, size_t ws_size,
                              hipStream_t stream) {
    const float* x  = (const float*)d_in[0];
    const int*   qw = (const int*)d_in[1];
    const float* sc = (const float*)d_in[2];
    float* out = (float*)d_out;

    unsigned short* xbf = (unsigned short*)d_ws;                               // 64 MiB
    unsigned short* wt  = (unsigned short*)((char*)d_ws + (size_t)M_DIM * K_DIM * 2); // 32 MiB

    cvt_x_bf16<<<(M_DIM * (size_t)K_DIM) / 8 / 256, 256, 0, stream>>>(x, xbf);
    dequant_wt<<<(K_DIM / 8 / 16) * (N_DIM / 16), 256, 0, stream>>>(qw, sc, wt);
    gemm_bf16_bt<<<(M_DIM / BM) * (N_DIM / BN), 256, 0, stream>>>(xbf, wt, out);
}

// Round 3
// 501.942 us; speedup vs baseline: 1.2464x; 1.0455x over previous
//
#include <hip/hip_runtime.h>
#include <hip/hip_bf16.h>
#include <stdint.h>

// R3: GPTQ int4 dequant + GEMM, M=8192 K=4096 N=4096, fp32 in/out.
// GEMM rewritten to the 256x256 8-phase schedule (T3+T4 counted vmcnt, T5
// setprio). LDS [2 buf][2 k-half][256][32] bf16 per matrix (128 KiB total),
// 64-B row stride -> ds_read_b128 frags conflict-free without swizzle,
// global_load_lds stays linear. Stage pipeline: ph1 -> A1/B1(t+1),
// ph3 -> A0/B0(t+2), vmcnt(4) at phases 4/8 only.
// Prepasses unchanged (x->bf16, unpack W->W^T bf16). ws: 96 MiB.

#define M_DIM 8192
#define K_DIM 4096
#define N_DIM 4096

typedef __attribute__((ext_vector_type(8))) short s16x8;
typedef __attribute__((ext_vector_type(8))) unsigned short u16x8;
typedef __attribute__((ext_vector_type(4))) float f32x4;
typedef unsigned int u32;

#define AS1 __attribute__((address_space(1)))
#define AS3 __attribute__((address_space(3)))

__device__ __forceinline__ void gload_lds16(const void* g, void* l) {
    __builtin_amdgcn_global_load_lds((const AS1 u32*)g, (AS3 u32*)l, 16, 0, 0);
}

__device__ __forceinline__ unsigned short f32_to_bf16_rne(float f) {
    union { float f; u32 u; } v; v.f = f;
    u32 u = v.u;
    u32 r = (u + 0x7FFFu + ((u >> 16) & 1u)) >> 16;
    return (unsigned short)r;
}

// ---- pre-pass 1: x fp32 -> bf16, [M][K] row-major. 8 elems/thread. ----
__global__ __launch_bounds__(256) void cvt_x_bf16(const float* __restrict__ in,
                                                  unsigned short* __restrict__ out) {
    const int i = blockIdx.x * 256 + threadIdx.x;
    const f32x4* p = (const f32x4*)in + (size_t)i * 2;
    f32x4 a = p[0], b = p[1];
    u16x8 r;
    r[0] = f32_to_bf16_rne(a[0]); r[1] = f32_to_bf16_rne(a[1]);
    r[2] = f32_to_bf16_rne(a[2]); r[3] = f32_to_bf16_rne(a[3]);
    r[4] = f32_to_bf16_rne(b[0]); r[5] = f32_to_bf16_rne(b[1]);
    r[6] = f32_to_bf16_rne(b[2]); r[7] = f32_to_bf16_rne(b[3]);
    ((u16x8*)out)[i] = r;
}

// ---- pre-pass 2: unpack GPTQ nibbles, dequant, store W^T bf16 [N][K]. ----
__global__ __launch_bounds__(256) void dequant_wt(const int* __restrict__ qw,
                                                  const float* __restrict__ scales,
                                                  unsigned short* __restrict__ wt) {
    const int bid = blockIdx.x;
    const int nb  = (bid & (N_DIM / 16 - 1)) * 16;
    const int kpb = (bid >> 8) * 16;
    const int tid = threadIdx.x;
    const int n   = nb + ((tid >> 6) << 2) + (tid & 3);
    const int kp  = kpb + ((tid >> 2) & 15);
    const u32 q = ((const u32*)qw)[(size_t)kp * N_DIM + n];
    const float s = scales[(size_t)(kp >> 4) * N_DIM + n];
    u16x8 r;
#pragma unroll
    for (int j = 0; j < 8; j++) {
        const int w = (int)((q >> (4 * j)) & 0xFu) - 8;
        r[j] = f32_to_bf16_rne((float)w * s);
    }
    *(u16x8*)(&wt[(size_t)n * K_DIM + (size_t)kp * 8]) = r;
}

// ---- GEMM: C[M][N] fp32 = A[M][K]bf16 * Bt[N][K]bf16^T, 256x256 8-phase ----
// 512 thr = 8 waves (wr=wave>>2 in 0..1, wc=wave&3 in 0..3), wave owns 128x64.
// acc[8][4] f32x4. Per K-tile (BK=64): 4 phases = (khalf, Mhalf), 16 MFMA each.

#define DS_A(BUF,KH,MH,mm) (*(const s16x8*)(pA + (BUF)*16384 + (KH)*8192 + (MH)*2048 + (mm)*512))
#define DS_B(BUF,KH,n)     (*(const s16x8*)(pB + (BUF)*16384 + (KH)*8192 + (n)*512))

#define STAGE4(BUF,KH,GK) do { int gk_ = (GK); if (gk_ > K_DIM - 32) gk_ = K_DIM - 32; \
    gload_lds16(gA0 + gk_, ldsA + ((BUF)*2+(KH))*8192 + dstL);                          \
    gload_lds16(gA1 + gk_, ldsA + ((BUF)*2+(KH))*8192 + dstH);                          \
    gload_lds16(gB0 + gk_, ldsB + ((BUF)*2+(KH))*8192 + dstL);                          \
    gload_lds16(gB1 + gk_, ldsB + ((BUF)*2+(KH))*8192 + dstH); } while (0)

#define MROW(MH,mm,AREG)                                                                      \
    acc[(MH)*4+(mm)][0] = __builtin_amdgcn_mfma_f32_16x16x32_bf16(AREG, bf0, acc[(MH)*4+(mm)][0], 0, 0, 0); \
    acc[(MH)*4+(mm)][1] = __builtin_amdgcn_mfma_f32_16x16x32_bf16(AREG, bf1, acc[(MH)*4+(mm)][1], 0, 0, 0); \
    acc[(MH)*4+(mm)][2] = __builtin_amdgcn_mfma_f32_16x16x32_bf16(AREG, bf2, acc[(MH)*4+(mm)][2], 0, 0, 0); \
    acc[(MH)*4+(mm)][3] = __builtin_amdgcn_mfma_f32_16x16x32_bf16(AREG, bf3, acc[(MH)*4+(mm)][3], 0, 0, 0);

#define NOOP ((void)0)

#define PHASE(BUF,KH,MH,LOADB,STAGE_STMT,TAIL_STMT)              \
    {                                                            \
        if (LOADB) {                                             \
            bf0 = DS_B(BUF,KH,0); bf1 = DS_B(BUF,KH,1);          \
            bf2 = DS_B(BUF,KH,2); bf3 = DS_B(BUF,KH,3);          \
        }                                                        \
        a0 = DS_A(BUF,KH,MH,0); a1 = DS_A(BUF,KH,MH,1);          \
        a2 = DS_A(BUF,KH,MH,2); a3 = DS_A(BUF,KH,MH,3);          \
        STAGE_STMT;                                              \
        __builtin_amdgcn_s_barrier();                            \
        asm volatile("s_waitcnt lgkmcnt(0)" ::: "memory");       \
        __builtin_amdgcn_sched_barrier(0);                       \
        __builtin_amdgcn_s_setprio(1);                           \
        MROW(MH,0,a0) MROW(MH,1,a1) MROW(MH,2,a2) MROW(MH,3,a3)  \
        __builtin_amdgcn_s_setprio(0);                           \
        TAIL_STMT;                                               \
        __builtin_amdgcn_s_barrier();                            \
    }

#define VMC4 asm volatile("s_waitcnt vmcnt(4)" ::: "memory")

__global__ __launch_bounds__(512, 2) void gemm_bf16_8ph(const unsigned short* __restrict__ A,
                                                        const unsigned short* __restrict__ Bt,
                                                        float* __restrict__ C) {
    __shared__ unsigned short As[2 * 2 * 8192];   // [buf][khalf][256 rows][32 k] bf16, 64 KiB
    __shared__ unsigned short Bs[2 * 2 * 8192];   // same for B^T rows (cols of C)

    const int tid  = threadIdx.x;
    const int wave = tid >> 6;
    const int lane = tid & 63;

    // XCD-aware bijective swizzle (nwg = 512, divisible by 8).
    const int bid = blockIdx.x;
    const int wg  = (bid & 7) * (512 / 8) + (bid >> 3);
    const int m0 = (wg >> 4) * 256;               // 32 m-tiles
    const int n0 = (wg & 15) * 256;               // 16 n-tiles

    const int wr = wave >> 2;                     // 0..1 -> rows wr*128..+127
    const int wc = wave & 3;                      // 0..3 -> cols wc*64..+63

    // staging addresses: call L covers tile rows 0..127, call H rows 128..255;
    // wave covers 16 rows (1 KiB), lane -> row lane>>2, col-octet lane&3.
    unsigned short* ldsA = &As[0];
    unsigned short* ldsB = &Bs[0];
    const int dstL = wave * 512;                  // elements
    const int dstH = 4096 + wave * 512;
    const unsigned short* gA0 = A  + (size_t)(m0 + wave * 16 + (lane >> 2)) * K_DIM + (lane & 3) * 8;
    const unsigned short* gA1 = gA0 + (size_t)128 * K_DIM;
    const unsigned short* gB0 = Bt + (size_t)(n0 + wave * 16 + (lane >> 2)) * K_DIM + (lane & 3) * 8;
    const unsigned short* gB1 = gB0 + (size_t)128 * K_DIM;

    // fragment bases (elements): row stride 32, frag: row = base + fr, k-octet fq
    const int fr = lane & 15;
    const int fq = lane >> 4;
    const unsigned short* pA = ldsA + (wr * 128 + fr) * 32 + fq * 8;
    const unsigned short* pB = ldsB + (wc * 64 + fr) * 32 + fq * 8;

    f32x4 acc[8][4] = {};
    s16x8 a0, a1, a2, a3, bf0, bf1, bf2, bf3;

    // prologue: K-tile 0 (both halves) + K-tile 1 k-low. 12 loads; keep 4 in flight.
    STAGE4(0, 0, 0);
    STAGE4(0, 1, 32);
    STAGE4(1, 0, 64);
    VMC4;
    __builtin_amdgcn_s_barrier();

    for (int kb = 0; kb < K_DIM; kb += 128) {     // 2 K-tiles per iteration
        // K-tile t (buf0)
        PHASE(0, 0, 0, 1, STAGE4(1, 1, kb + 96),  NOOP);   // stage A1/B1(t+1)
        PHASE(0, 0, 1, 0, NOOP,                   NOOP);
        PHASE(0, 1, 0, 1, STAGE4(0, 0, kb + 128), NOOP);   // stage A0/B0(t+2)
        PHASE(0, 1, 1, 0, NOOP,                   VMC4);
        // K-tile t+1 (buf1)
        PHASE(1, 0, 0, 1, STAGE4(0, 1, kb + 160), NOOP);   // stage A1/B1(t+2)
        PHASE(1, 0, 1, 0, NOOP,                   NOOP);
        PHASE(1, 1, 0, 1, STAGE4(1, 0, kb + 192), NOOP);   // stage A0/B0(t+3)
        PHASE(1, 1, 1, 0, NOOP,                   VMC4);
    }

    // drain staging loads before LDS dealloc / epilogue.
    asm volatile("s_waitcnt vmcnt(0)" ::: "memory");

    // epilogue: C/D layout col=lane&15, row=(lane>>4)*4+reg (m89-verified).
#pragma unroll
    for (int mh = 0; mh < 2; mh++)
#pragma unroll
        for (int mm = 0; mm < 4; mm++) {
            const int row = m0 + wr * 128 + mh * 64 + mm * 16 + fq * 4;
#pragma unroll
            for (int n = 0; n < 4; n++) {
                const int col = n0 + wc * 64 + n * 16 + fr;
                float* cp = C + (size_t)row * N_DIM + col;
#pragma unroll
                for (int r = 0; r < 4; r++) cp[(size_t)r * N_DIM] = acc[mh * 4 + mm][n][r];
            }
        }
}

extern "C" void kernel_launch(void* const* d_in, const int* in_sizes, int n_in,
                              void* d_out, int out_size, void* d_ws, size_t ws_size,
                              hipStream_t stream) {
    const float* x  = (const float*)d_in[0];
    const int*   qw = (const int*)d_in[1];
    const float* sc = (const float*)d_in[2];
    float* out = (float*)d_out;

    unsigned short* xbf = (unsigned short*)d_ws;                                      // 64 MiB
    unsigned short* wt  = (unsigned short*)((char*)d_ws + (size_t)M_DIM * K_DIM * 2); // 32 MiB

    cvt_x_bf16<<<(M_DIM * (size_t)K_DIM) / 8 / 256, 256, 0, stream>>>(x, xbf);
    dequant_wt<<<(K_DIM / 8 / 16) * (N_DIM / 16), 256, 0, stream>>>(qw, sc, wt);
    gemm_bf16_8ph<<<(M_DIM / 256) * (N_DIM / 256), 512, 0, stream>>>(xbf, wt, out);
}

// Round 5
// 500.997 us; speedup vs baseline: 1.2488x; 1.0019x over previous
//
#include <hip/hip_runtime.h>
#include <hip/hip_bf16.h>
#include <stdint.h>

// R5 (= R4 resubmit; previous round was an infra failure, kernel unmeasured).
// GPTQ int4 dequant + GEMM, M=8192 K=4096 N=4096, fp32 in/out.
// R3 8-phase schedule + T2 octet XOR-swizzle (both sides): R3's [*][32] LDS
// rows were half-wave bank-imbalanced (lanes 0-31 hit only 16 banks ->
// 2.5e7 conflict cycles). Slot(row, o) now holds global k-octet o^(row&3):
// staging pre-swizzles the global source octet (global_load_lds dest linear,
// rule #21), fragment reads XOR fq by fr&3. Schedule unchanged from R3.
// ws: 96 MiB.

#define M_DIM 8192
#define K_DIM 4096
#define N_DIM 4096

typedef __attribute__((ext_vector_type(8))) short s16x8;
typedef __attribute__((ext_vector_type(8))) unsigned short u16x8;
typedef __attribute__((ext_vector_type(4))) float f32x4;
typedef unsigned int u32;

#define AS1 __attribute__((address_space(1)))
#define AS3 __attribute__((address_space(3)))

__device__ __forceinline__ void gload_lds16(const void* g, void* l) {
    __builtin_amdgcn_global_load_lds((const AS1 u32*)g, (AS3 u32*)l, 16, 0, 0);
}

__device__ __forceinline__ unsigned short f32_to_bf16_rne(float f) {
    union { float f; u32 u; } v; v.f = f;
    u32 u = v.u;
    u32 r = (u + 0x7FFFu + ((u >> 16) & 1u)) >> 16;
    return (unsigned short)r;
}

// ---- pre-pass 1: x fp32 -> bf16, [M][K] row-major. 8 elems/thread. ----
__global__ __launch_bounds__(256) void cvt_x_bf16(const float* __restrict__ in,
                                                  unsigned short* __restrict__ out) {
    const int i = blockIdx.x * 256 + threadIdx.x;
    const f32x4* p = (const f32x4*)in + (size_t)i * 2;
    f32x4 a = p[0], b = p[1];
    u16x8 r;
    r[0] = f32_to_bf16_rne(a[0]); r[1] = f32_to_bf16_rne(a[1]);
    r[2] = f32_to_bf16_rne(a[2]); r[3] = f32_to_bf16_rne(a[3]);
    r[4] = f32_to_bf16_rne(b[0]); r[5] = f32_to_bf16_rne(b[1]);
    r[6] = f32_to_bf16_rne(b[2]); r[7] = f32_to_bf16_rne(b[3]);
    ((u16x8*)out)[i] = r;
}

// ---- pre-pass 2: unpack GPTQ nibbles, dequant, store W^T bf16 [N][K]. ----
__global__ __launch_bounds__(256) void dequant_wt(const int* __restrict__ qw,
                                                  const float* __restrict__ scales,
                                                  unsigned short* __restrict__ wt) {
    const int bid = blockIdx.x;
    const int nb  = (bid & (N_DIM / 16 - 1)) * 16;
    const int kpb = (bid >> 8) * 16;
    const int tid = threadIdx.x;
    const int n   = nb + ((tid >> 6) << 2) + (tid & 3);
    const int kp  = kpb + ((tid >> 2) & 15);
    const u32 q = ((const u32*)qw)[(size_t)kp * N_DIM + n];
    const float s = scales[(size_t)(kp >> 4) * N_DIM + n];
    u16x8 r;
#pragma unroll
    for (int j = 0; j < 8; j++) {
        const int w = (int)((q >> (4 * j)) & 0xFu) - 8;
        r[j] = f32_to_bf16_rne((float)w * s);
    }
    *(u16x8*)(&wt[(size_t)n * K_DIM + (size_t)kp * 8]) = r;
}

// ---- GEMM: C[M][N] fp32 = A[M][K]bf16 * Bt[N][K]bf16^T, 256x256 8-phase ----
// 512 thr = 8 waves (wr=wave>>2 in 0..1, wc=wave&3 in 0..3), wave owns 128x64.
// LDS [2 buf][2 khalf][256 rows][32 k] per matrix; slot(row,o)=octet o^(row&3).

#define DS_A(BUF,KH,MH,mm) (*(const s16x8*)(pA + (BUF)*16384 + (KH)*8192 + (MH)*2048 + (mm)*512))
#define DS_B(BUF,KH,n)     (*(const s16x8*)(pB + (BUF)*16384 + (KH)*8192 + (n)*512))

#define STAGE4(BUF,KH,GK) do { int gk_ = (GK); if (gk_ > K_DIM - 32) gk_ = K_DIM - 32; \
    gload_lds16(gA0 + gk_, ldsA + ((BUF)*2+(KH))*8192 + dstL);                          \
    gload_lds16(gA1 + gk_, ldsA + ((BUF)*2+(KH))*8192 + dstH);                          \
    gload_lds16(gB0 + gk_, ldsB + ((BUF)*2+(KH))*8192 + dstL);                          \
    gload_lds16(gB1 + gk_, ldsB + ((BUF)*2+(KH))*8192 + dstH); } while (0)

#define MROW(MH,mm,AREG)                                                                      \
    acc[(MH)*4+(mm)][0] = __builtin_amdgcn_mfma_f32_16x16x32_bf16(AREG, bf0, acc[(MH)*4+(mm)][0], 0, 0, 0); \
    acc[(MH)*4+(mm)][1] = __builtin_amdgcn_mfma_f32_16x16x32_bf16(AREG, bf1, acc[(MH)*4+(mm)][1], 0, 0, 0); \
    acc[(MH)*4+(mm)][2] = __builtin_amdgcn_mfma_f32_16x16x32_bf16(AREG, bf2, acc[(MH)*4+(mm)][2], 0, 0, 0); \
    acc[(MH)*4+(mm)][3] = __builtin_amdgcn_mfma_f32_16x16x32_bf16(AREG, bf3, acc[(MH)*4+(mm)][3], 0, 0, 0);

#define NOOP ((void)0)

#define PHASE(BUF,KH,MH,LOADB,STAGE_STMT,TAIL_STMT)              \
    {                                                            \
        if (LOADB) {                                             \
            bf0 = DS_B(BUF,KH,0); bf1 = DS_B(BUF,KH,1);          \
            bf2 = DS_B(BUF,KH,2); bf3 = DS_B(BUF,KH,3);          \
        }                                                        \
        a0 = DS_A(BUF,KH,MH,0); a1 = DS_A(BUF,KH,MH,1);          \
        a2 = DS_A(BUF,KH,MH,2); a3 = DS_A(BUF,KH,MH,3);          \
        STAGE_STMT;                                              \
        __builtin_amdgcn_s_barrier();                            \
        asm volatile("s_waitcnt lgkmcnt(0)" ::: "memory");       \
        __builtin_amdgcn_sched_barrier(0);                       \
        __builtin_amdgcn_s_setprio(1);                           \
        MROW(MH,0,a0) MROW(MH,1,a1) MROW(MH,2,a2) MROW(MH,3,a3)  \
        __builtin_amdgcn_s_setprio(0);                           \
        TAIL_STMT;                                               \
        __builtin_amdgcn_s_barrier();                            \
    }

#define VMC4 asm volatile("s_waitcnt vmcnt(4)" ::: "memory")

__global__ __launch_bounds__(512, 2) void gemm_bf16_8ph(const unsigned short* __restrict__ A,
                                                        const unsigned short* __restrict__ Bt,
                                                        float* __restrict__ C) {
    __shared__ unsigned short As[2 * 2 * 8192];   // [buf][khalf][256 rows][32 k] bf16, 64 KiB
    __shared__ unsigned short Bs[2 * 2 * 8192];

    const int tid  = threadIdx.x;
    const int wave = tid >> 6;
    const int lane = tid & 63;

    // XCD-aware bijective swizzle (nwg = 512, divisible by 8).
    const int bid = blockIdx.x;
    const int wg  = (bid & 7) * (512 / 8) + (bid >> 3);
    const int m0 = (wg >> 4) * 256;               // 32 m-tiles
    const int n0 = (wg & 15) * 256;               // 16 n-tiles

    const int wr = wave >> 2;                     // 0..1 -> rows wr*128..+127
    const int wc = wave & 3;                      // 0..3 -> cols wc*64..+63

    // staging: wave covers 16 rows (1 KiB) per call; lane -> row lane>>2,
    // SOURCE octet pre-swizzled: (lane&3) ^ (row&3) so LDS slot(row,o) holds
    // global octet o^(row&3) while the global_load_lds dest stays linear.
    unsigned short* ldsA = &As[0];
    unsigned short* ldsB = &Bs[0];
    const int dstL = wave * 512;                  // elements
    const int dstH = 4096 + wave * 512;
    const int scol = ((lane & 3) ^ ((lane >> 2) & 3)) * 8;
    const unsigned short* gA0 = A  + (size_t)(m0 + wave * 16 + (lane >> 2)) * K_DIM + scol;
    const unsigned short* gA1 = gA0 + (size_t)128 * K_DIM;
    const unsigned short* gB0 = Bt + (size_t)(n0 + wave * 16 + (lane >> 2)) * K_DIM + scol;
    const unsigned short* gB1 = gB0 + (size_t)128 * K_DIM;

    // fragment bases: row stride 32 elems; read octet = fq ^ (fr&3) (matches
    // the write-side involution; row ≡ fr mod 4 in every subregion).
    const int fr = lane & 15;
    const int fq = lane >> 4;
    const unsigned short* pA = ldsA + (wr * 128 + fr) * 32 + ((fq ^ (fr & 3)) << 3);
    const unsigned short* pB = ldsB + (wc * 64 + fr) * 32 + ((fq ^ (fr & 3)) << 3);

    f32x4 acc[8][4] = {};
    s16x8 a0, a1, a2, a3, bf0, bf1, bf2, bf3;

    // prologue: K-tile 0 (both halves) + K-tile 1 k-low. 12 loads; keep 4 in flight.
    STAGE4(0, 0, 0);
    STAGE4(0, 1, 32);
    STAGE4(1, 0, 64);
    VMC4;
    __builtin_amdgcn_s_barrier();

    for (int kb = 0; kb < K_DIM; kb += 128) {     // 2 K-tiles per iteration
        // K-tile t (buf0)
        PHASE(0, 0, 0, 1, STAGE4(1, 1, kb + 96),  NOOP);   // stage A1/B1(t+1)
        PHASE(0, 0, 1, 0, NOOP,                   NOOP);
        PHASE(0, 1, 0, 1, STAGE4(0, 0, kb + 128), NOOP);   // stage A0/B0(t+2)
        PHASE(0, 1, 1, 0, NOOP,                   VMC4);
        // K-tile t+1 (buf1)
        PHASE(1, 0, 0, 1, STAGE4(0, 1, kb + 160), NOOP);   // stage A1/B1(t+2)
        PHASE(1, 0, 1, 0, NOOP,                   NOOP);
        PHASE(1, 1, 0, 1, STAGE4(1, 0, kb + 192), NOOP);   // stage A0/B0(t+3)
        PHASE(1, 1, 1, 0, NOOP,                   VMC4);
    }

    // drain staging loads before LDS dealloc / epilogue.
    asm volatile("s_waitcnt vmcnt(0)" ::: "memory");

    // epilogue: C/D layout col=lane&15, row=(lane>>4)*4+reg (m89-verified).
#pragma unroll
    for (int mh = 0; mh < 2; mh++)
#pragma unroll
        for (int mm = 0; mm < 4; mm++) {
            const int row = m0 + wr * 128 + mh * 64 + mm * 16 + fq * 4;
#pragma unroll
            for (int n = 0; n < 4; n++) {
                const int col = n0 + wc * 64 + n * 16 + fr;
                float* cp = C + (size_t)row * N_DIM + col;
#pragma unroll
                for (int r = 0; r < 4; r++) cp[(size_t)r * N_DIM] = acc[mh * 4 + mm][n][r];
            }
        }
}

extern "C" void kernel_launch(void* const* d_in, const int* in_sizes, int n_in,
                              void* d_out, int out_size, void* d_ws, size_t ws_size,
                              hipStream_t stream) {
    const float* x  = (const float*)d_in[0];
    const int*   qw = (const int*)d_in[1];
    const float* sc = (const float*)d_in[2];
    float* out = (float*)d_out;

    unsigned short* xbf = (unsigned short*)d_ws;                                      // 64 MiB
    unsigned short* wt  = (unsigned short*)((char*)d_ws + (size_t)M_DIM * K_DIM * 2); // 32 MiB

    cvt_x_bf16<<<(M_DIM * (size_t)K_DIM) / 8 / 256, 256, 0, stream>>>(x, xbf);
    dequant_wt<<<(K_DIM / 8 / 16) * (N_DIM / 16), 256, 0, stream>>>(qw, sc, wt);
    gemm_bf16_8ph<<<(M_DIM / 256) * (N_DIM / 256), 512, 0, stream>>>(xbf, wt, out);
}

// Round 7
// 476.461 us; speedup vs baseline: 1.3131x; 1.0515x over previous
//
#include <hip/hip_runtime.h>
#include <hip/hip_bf16.h>
#include <stdint.h>

// R7 (= R6 resubmit; round 6 was an infra failure, kernel unmeasured).
// GPTQ int4 dequant + GEMM, M=8192 K=4096 N=4096, fp32 in/out.
// GEMM restructured: 256x256 wg tile, 4 waves (2x2), per-wave 128x128,
// acc[8][8] f32x4 (256 regs). Rationale: R3-R5 were LDS-BW-bound (read
// amplification 3x -> 40% MfmaUtil ceiling); 2x amplification raises the
// ceiling to ~62-80%. 1 wave/SIMD, so fragment ds_reads are pipelined one
// phase ahead (issued post-MFMA, waited at next phase's lgkmcnt(0)).
// 2 phases per K-tile (kh0, kh1), 64 MFMA each. Counted vmcnt(8) at ph2/ph4.
// Same octet swizzle as R5; same region double-buffer schedule (re-verified).
// ws: 96 MiB.

#define M_DIM 8192
#define K_DIM 4096
#define N_DIM 4096

typedef __attribute__((ext_vector_type(8))) short s16x8;
typedef __attribute__((ext_vector_type(8))) unsigned short u16x8;
typedef __attribute__((ext_vector_type(4))) float f32x4;
typedef unsigned int u32;

#define AS1 __attribute__((address_space(1)))
#define AS3 __attribute__((address_space(3)))

__device__ __forceinline__ void gload_lds16(const void* g, void* l) {
    __builtin_amdgcn_global_load_lds((const AS1 u32*)g, (AS3 u32*)l, 16, 0, 0);
}

__device__ __forceinline__ unsigned short f32_to_bf16_rne(float f) {
    union { float f; u32 u; } v; v.f = f;
    u32 u = v.u;
    u32 r = (u + 0x7FFFu + ((u >> 16) & 1u)) >> 16;
    return (unsigned short)r;
}

// ---- pre-pass 1: x fp32 -> bf16, [M][K] row-major. 8 elems/thread. ----
__global__ __launch_bounds__(256) void cvt_x_bf16(const float* __restrict__ in,
                                                  unsigned short* __restrict__ out) {
    const int i = blockIdx.x * 256 + threadIdx.x;
    const f32x4* p = (const f32x4*)in + (size_t)i * 2;
    f32x4 a = p[0], b = p[1];
    u16x8 r;
    r[0] = f32_to_bf16_rne(a[0]); r[1] = f32_to_bf16_rne(a[1]);
    r[2] = f32_to_bf16_rne(a[2]); r[3] = f32_to_bf16_rne(a[3]);
    r[4] = f32_to_bf16_rne(b[0]); r[5] = f32_to_bf16_rne(b[1]);
    r[6] = f32_to_bf16_rne(b[2]); r[7] = f32_to_bf16_rne(b[3]);
    ((u16x8*)out)[i] = r;
}

// ---- pre-pass 2: unpack GPTQ nibbles, dequant, store W^T bf16 [N][K]. ----
__global__ __launch_bounds__(256) void dequant_wt(const int* __restrict__ qw,
                                                  const float* __restrict__ scales,
                                                  unsigned short* __restrict__ wt) {
    const int bid = blockIdx.x;
    const int nb  = (bid & (N_DIM / 16 - 1)) * 16;
    const int kpb = (bid >> 8) * 16;
    const int tid = threadIdx.x;
    const int n   = nb + ((tid >> 6) << 2) + (tid & 3);
    const int kp  = kpb + ((tid >> 2) & 15);
    const u32 q = ((const u32*)qw)[(size_t)kp * N_DIM + n];
    const float s = scales[(size_t)(kp >> 4) * N_DIM + n];
    u16x8 r;
#pragma unroll
    for (int j = 0; j < 8; j++) {
        const int w = (int)((q >> (4 * j)) & 0xFu) - 8;
        r[j] = f32_to_bf16_rne((float)w * s);
    }
    *(u16x8*)(&wt[(size_t)n * K_DIM + (size_t)kp * 8]) = r;
}

// ---- GEMM helpers ----
__device__ __forceinline__ void loadf(s16x8 (&a)[8], s16x8 (&b)[8],
                                      const unsigned short* pA,
                                      const unsigned short* pB, int reg_off) {
#pragma unroll
    for (int i = 0; i < 8; i++) {
        a[i] = *(const s16x8*)(pA + reg_off + i * 512);
        b[i] = *(const s16x8*)(pB + reg_off + i * 512);
    }
}

__device__ __forceinline__ void mfma64(const s16x8 (&a)[8], const s16x8 (&b)[8],
                                       f32x4 (&acc)[8][8]) {
#pragma unroll
    for (int m = 0; m < 8; m++)
#pragma unroll
        for (int n = 0; n < 8; n++)
            acc[m][n] = __builtin_amdgcn_mfma_f32_16x16x32_bf16(a[m], b[n], acc[m][n], 0, 0, 0);
}

// region byte layout (elems): (buf*2+kh)*8192, each [256 rows][32 k] bf16.
#define R00 0
#define R01 8192
#define R10 16384
#define R11 24576

#define STAGE8(BUF,KH,GK) do { int gk_ = (GK); if (gk_ > K_DIM - 32) gk_ = K_DIM - 32; \
    const int ro_ = ((BUF)*2+(KH))*8192 + wave*512;                                    \
    _Pragma("unroll")                                                                  \
    for (int j_ = 0; j_ < 4; j_++) {                                                   \
        gload_lds16(gA0 + (size_t)(j_*64)*K_DIM + gk_, ldsA + ro_ + j_*2048);          \
        gload_lds16(gB0 + (size_t)(j_*64)*K_DIM + gk_, ldsB + ro_ + j_*2048);          \
    } } while (0)

#define BARR()  __builtin_amdgcn_s_barrier()
#define LGKM0() do { asm volatile("s_waitcnt lgkmcnt(0)" ::: "memory"); \
                     __builtin_amdgcn_sched_barrier(0); } while (0)
#define SBAR()  __builtin_amdgcn_sched_barrier(0)
#define VMC8    asm volatile("s_waitcnt vmcnt(8)" ::: "memory")
#define VMC0    asm volatile("s_waitcnt vmcnt(0)" ::: "memory")

// ---- GEMM: C[M][N] fp32 = A[M][K]bf16 * Bt[N][K]bf16^T ----
__global__ __launch_bounds__(256, 1) void gemm_bf16_4w(const unsigned short* __restrict__ A,
                                                       const unsigned short* __restrict__ Bt,
                                                       float* __restrict__ C) {
    __shared__ unsigned short As[2 * 2 * 8192];   // 64 KiB
    __shared__ unsigned short Bs[2 * 2 * 8192];   // 64 KiB

    const int tid  = threadIdx.x;
    const int wave = tid >> 6;                    // 0..3
    const int lane = tid & 63;

    // XCD-aware bijective swizzle (nwg = 512, divisible by 8).
    const int bid = blockIdx.x;
    const int wg  = (bid & 7) * (512 / 8) + (bid >> 3);
    const int m0 = (wg >> 4) * 256;               // 32 m-tiles
    const int n0 = (wg & 15) * 256;               // 16 n-tiles

    const int wr = wave >> 1;                     // 0..1 -> rows wr*128..+127
    const int wc = wave & 1;                      // 0..1 -> cols wc*128..+127

    // staging: 256 thr, round j covers rows j*64..+63; thread t -> row t>>2,
    // source octet (t&3)^(row&3) (write-side of the involution), dest linear.
    unsigned short* ldsA = &As[0];
    unsigned short* ldsB = &Bs[0];
    const int srow  = tid >> 2;                   // 0..63
    const int scol8 = ((tid & 3) ^ (srow & 3)) * 8;
    const unsigned short* gA0 = A  + (size_t)(m0 + srow) * K_DIM + scol8;
    const unsigned short* gB0 = Bt + (size_t)(n0 + srow) * K_DIM + scol8;

    // fragment read bases: row = base + fr (stride 32 elems), octet fq^(fr&3).
    const int fr = lane & 15;
    const int fq = lane >> 4;
    const unsigned short* pA = ldsA + (wr * 128 + fr) * 32 + ((fq ^ (fr & 3)) << 3);
    const unsigned short* pB = ldsB + (wc * 128 + fr) * 32 + ((fq ^ (fr & 3)) << 3);

    f32x4 acc[8][8] = {};
    s16x8 aR[8], bR[8], aS[8], bS[8];

    // prologue: stage t0 both halves + t1 kh0; land kh0+kh1; read ph1 frags.
    STAGE8(0, 0, 0);
    STAGE8(0, 1, 32);
    STAGE8(1, 0, 64);
    VMC8;                                         // (0,0) and (0,1) landed
    BARR();
    loadf(aR, bR, pA, pB, R00);

    for (int kb = 0; kb < K_DIM; kb += 128) {     // 2 K-tiles per iteration
        // ph1: tile t, kh0 (buf0) — cur=R
        STAGE8(1, 1, kb + 96);
        BARR(); LGKM0();
        __builtin_amdgcn_s_setprio(1); mfma64(aR, bR, acc); __builtin_amdgcn_s_setprio(0);
        loadf(aS, bS, pA, pB, R01); SBAR();
        BARR();
        // ph2: tile t, kh1 — cur=S
        STAGE8(0, 0, kb + 128);
        BARR(); LGKM0();
        __builtin_amdgcn_s_setprio(1); mfma64(aS, bS, acc); __builtin_amdgcn_s_setprio(0);
        VMC8;
        loadf(aR, bR, pA, pB, R10); SBAR();
        BARR();
        // ph3: tile t+1, kh0 (buf1) — cur=R
        STAGE8(0, 1, kb + 160);
        BARR(); LGKM0();
        __builtin_amdgcn_s_setprio(1); mfma64(aR, bR, acc); __builtin_amdgcn_s_setprio(0);
        loadf(aS, bS, pA, pB, R11); SBAR();
        BARR();
        // ph4: tile t+1, kh1 — cur=S
        STAGE8(1, 0, kb + 192);
        BARR(); LGKM0();
        __builtin_amdgcn_s_setprio(1); mfma64(aS, bS, acc); __builtin_amdgcn_s_setprio(0);
        VMC8;
        loadf(aR, bR, pA, pB, R00); SBAR();
        BARR();
    }

    VMC0;                                         // drain before LDS dealloc

    // epilogue: C/D layout col=lane&15, row=(lane>>4)*4+reg (m89-verified).
#pragma unroll
    for (int m = 0; m < 8; m++) {
        const int row = m0 + wr * 128 + m * 16 + fq * 4;
#pragma unroll
        for (int n = 0; n < 8; n++) {
            const int col = n0 + wc * 128 + n * 16 + fr;
            float* cp = C + (size_t)row * N_DIM + col;
#pragma unroll
            for (int r = 0; r < 4; r++) cp[(size_t)r * N_DIM] = acc[m][n][r];
        }
    }
}

extern "C" void kernel_launch(void* const* d_in, const int* in_sizes, int n_in,
                              void* d_out, int out_size, void* d_ws, size_t ws_size,
                              hipStream_t stream) {
    const float* x  = (const float*)d_in[0];
    const int*   qw = (const int*)d_in[1];
    const float* sc = (const float*)d_in[2];
    float* out = (float*)d_out;

    unsigned short* xbf = (unsigned short*)d_ws;                                      // 64 MiB
    unsigned short* wt  = (unsigned short*)((char*)d_ws + (size_t)M_DIM * K_DIM * 2); // 32 MiB

    cvt_x_bf16<<<(M_DIM * (size_t)K_DIM) / 8 / 256, 256, 0, stream>>>(x, xbf);
    dequant_wt<<<(K_DIM / 8 / 16) * (N_DIM / 16), 256, 0, stream>>>(qw, sc, wt);
    gemm_bf16_4w<<<(M_DIM / 256) * (N_DIM / 256), 256, 0, stream>>>(xbf, wt, out);
}